// Round 1
// baseline (370.750 us; speedup 1.0000x reference)
//
#include <hip/hip_runtime.h>
#include <hip/hip_bf16.h>

// Problem constants (from setup_inputs): B=4, T=4096, D=1024, H=1024
#define B_ 4
#define T_ 4096
#define D_ 1024
#define H_ 1024
#define M_ (B_ * T_)   // 16384

typedef __attribute__((ext_vector_type(8))) short short8;   // 8 bf16 = 4 VGPRs (MFMA A/B frag)
typedef __attribute__((ext_vector_type(4))) float f32x4;    // MFMA C/D frag

// ---------------- fp32 -> bf16 (RNE) convert, vectorized ----------------
__device__ __forceinline__ unsigned short f2bf(float f) {
    unsigned int u = __float_as_uint(f);
    u += 0x7fffu + ((u >> 16) & 1u);
    return (unsigned short)(u >> 16);
}

__global__ void convert_kernel(const float* __restrict__ src,
                               unsigned short* __restrict__ dst, int n4) {
    int i = blockIdx.x * blockDim.x + threadIdx.x;
    if (i >= n4) return;
    float4 f = ((const float4*)src)[i];
    ushort4 u;
    u.x = f2bf(f.x); u.y = f2bf(f.y); u.z = f2bf(f.z); u.w = f2bf(f.w);
    ((ushort4*)dst)[i] = u;
}

// ---------------- fused dual GEMM + epilogue -> (a, v) pairs ----------------
// C_z[m][n] = sum_k x[m][k] * Wz[n][k]; same for Wh.
// Epilogue: a = sigmoid(-k), v = sigmoid(k) * g(hb); store interleaved float2.
// Block tile: 64(M) x 64(N), 4 waves; wave w owns n-group w (16 cols), all 4 m-groups.
// MFMA 16x16x32 bf16. A staged via LDS in fragment order; B loaded direct to regs
// (thread (w,lane)'s B-fragment == the 16B it would stage: Wz[n=nb*64+w*16+(lane&15)][kk+(lane>>4)*8 ..+7]).
__global__ __launch_bounds__(256) void dual_gemm_kernel(
    const unsigned short* __restrict__ xb,   // [M][D] bf16
    const unsigned short* __restrict__ wzb,  // [H][D] bf16
    const unsigned short* __restrict__ whb,  // [H][D] bf16
    const float* __restrict__ bz,
    const float* __restrict__ bh,
    float* __restrict__ av)                  // [M][H][2] fp32
{
    __shared__ short8 lA[256];               // 4 m-groups x 64 lanes x 16B = 4 KB

    const int tid  = threadIdx.x;
    const int lane = tid & 63;
    const int w    = tid >> 6;               // wave id 0..3
    const int mb   = blockIdx.x >> 4;        // 0..255
    const int nb   = blockIdx.x & 15;        // 0..15
    const int r16  = lane & 15;
    const int q    = lane >> 4;              // 0..3

    const unsigned short* aptr = xb  + ((size_t)(mb * 64 + w * 16 + r16)) * D_ + q * 8;
    const unsigned short* zptr = wzb + ((size_t)(nb * 64 + w * 16 + r16)) * D_ + q * 8;
    const unsigned short* hptr = whb + ((size_t)(nb * 64 + w * 16 + r16)) * D_ + q * 8;

    f32x4 accz[4] = {};
    f32x4 acch[4] = {};

    for (int kk = 0; kk < D_; kk += 32) {
        short8 fbz = *(const short8*)(zptr + kk);   // own B frag, direct from global (L2-hot)
        short8 fbh = *(const short8*)(hptr + kk);
        short8 va  = *(const short8*)(aptr + kk);
        __syncthreads();                            // WAR: previous iter's lA reads done
        lA[tid] = va;                               // stage m-group w in fragment order
        __syncthreads();
#pragma unroll
        for (int gm = 0; gm < 4; ++gm) {
            short8 fa = lA[gm * 64 + lane];
            accz[gm] = __builtin_amdgcn_mfma_f32_16x16x32_bf16(fa, fbz, accz[gm], 0, 0, 0);
            acch[gm] = __builtin_amdgcn_mfma_f32_16x16x32_bf16(fa, fbh, acch[gm], 0, 0, 0);
        }
    }

    // Epilogue. C/D layout: col = lane&15, row = (lane>>4)*4 + rr  [verified m89/m91]
    const int ncol = nb * 64 + w * 16 + r16;
    const float bzv = bz[ncol];
    const float bhv = bh[ncol];
#pragma unroll
    for (int gm = 0; gm < 4; ++gm) {
#pragma unroll
        for (int rr = 0; rr < 4; ++rr) {
            const int row = q * 4 + rr;
            const size_t m = (size_t)mb * 64 + gm * 16 + row;
            float kv = accz[gm][rr] + bzv;
            float hv = acch[gm][rr] + bhv;
            // stable sigmoid pieces
            float tk = __expf(-fabsf(kv));
            float ik = 1.0f / (1.0f + tk);
            float sig = (kv >= 0.0f) ? ik : tk * ik;     // sigmoid(k)
            float ac  = (kv >= 0.0f) ? tk * ik : ik;     // sigmoid(-k) = 1 - sigmoid(k)
            float th = __expf(-fabsf(hv));
            float ih = 1.0f / (1.0f + th);
            float gh = (hv >= 0.0f) ? (hv + 0.5f) : th * ih;  // g(hb)
            float2 o;
            o.x = ac;
            o.y = sig * gh;
            *(float2*)(av + ((size_t)m * H_ + ncol) * 2) = o;
        }
    }
}

// ---------------- chunked scan: h_t = a_t * h_{t-1} + v_t ----------------
// 64 chunks x 64 steps. Pass1: per (b,n,chunk) compute affine composition (A,V).
__global__ __launch_bounds__(256) void scan_pass1(const float* __restrict__ av,
                                                  float2* __restrict__ chunkAV) {
    int g = blockIdx.x * blockDim.x + threadIdx.x;   // 262144 threads
    int n = g & (H_ - 1);
    int rest = g >> 10;        // 0..255
    int c = rest & 63;
    int b = rest >> 6;
    const float2* base = (const float2*)av + ((size_t)(b * T_ + c * 64)) * H_ + n;
    float A = 1.0f, V = 0.0f;
#pragma unroll 8
    for (int t = 0; t < 64; ++t) {
        float2 p = base[(size_t)t * H_];
        V = p.x * V + p.y;
        A = p.x * A;
    }
    chunkAV[c * 4096 + b * 1024 + n] = make_float2(A, V);
}

// Pass2: per channel, sequential over 64 chunk summaries; emit chunk-entry states.
__global__ __launch_bounds__(256) void scan_pass2(const float2* __restrict__ chunkAV,
                                                  const float* __restrict__ h0,
                                                  float* __restrict__ hstart) {
    int chan = blockIdx.x * blockDim.x + threadIdx.x;   // 4096 threads
    int n = chan & (H_ - 1);
    int b = chan >> 10;
    float x = h0[b * H_ + n];
    float h;
    if (x >= 0.0f) { h = x + 0.5f; }
    else { float t = __expf(x); h = t / (1.0f + t); }   // g(h0)
    for (int c = 0; c < 64; ++c) {
        hstart[c * 4096 + chan] = h;
        float2 s = chunkAV[c * 4096 + chan];
        h = s.x * h + s.y;
    }
}

// Pass3: replay each chunk from its entry state, writing h_1..h_T.
__global__ __launch_bounds__(256) void scan_pass3(const float* __restrict__ av,
                                                  const float* __restrict__ hstart,
                                                  float* __restrict__ out) {
    int g = blockIdx.x * blockDim.x + threadIdx.x;
    int n = g & (H_ - 1);
    int rest = g >> 10;
    int c = rest & 63;
    int b = rest >> 6;
    float h = hstart[c * 4096 + b * 1024 + n];
    const float2* base = (const float2*)av + ((size_t)(b * T_ + c * 64)) * H_ + n;
    float* obase = out + ((size_t)(b * T_ + c * 64)) * H_ + n;
#pragma unroll 8
    for (int t = 0; t < 64; ++t) {
        float2 p = base[(size_t)t * H_];
        h = p.x * h + p.y;
        obase[(size_t)t * H_] = h;
    }
}

// ---------------- launch ----------------
extern "C" void kernel_launch(void* const* d_in, const int* in_sizes, int n_in,
                              void* d_out, int out_size, void* d_ws, size_t ws_size,
                              hipStream_t stream) {
    const float* x  = (const float*)d_in[0];   // [B,T,D]
    const float* h0 = (const float*)d_in[1];   // [B,H]
    const float* Wz = (const float*)d_in[2];   // [H,D]
    const float* bz = (const float*)d_in[3];   // [H]
    const float* Wh = (const float*)d_in[4];   // [H,D]
    const float* bh = (const float*)d_in[5];   // [H]
    float* out = (float*)d_out;

    // workspace layout (bytes):
    //   xb  bf16 [M][D]            @ 0          33,554,432
    //   wzb bf16 [H][D]            @ 33554432    2,097,152
    //   whb bf16 [H][D]            @ 35651584    2,097,152
    //   av  fp32 [M][H][2]         @ 37748736  134,217,728
    //   chunkAV float2 [64][B][H]  @ 171966464   2,097,152
    //   hstart fp32 [64][B*H]      @ 174063616   1,048,576
    char* ws = (char*)d_ws;
    unsigned short* xb  = (unsigned short*)(ws);
    unsigned short* wzb = (unsigned short*)(ws + 33554432);
    unsigned short* whb = (unsigned short*)(ws + 35651584);
    float*  av          = (float*)(ws + 37748736);
    float2* chunkAV     = (float2*)(ws + 171966464);
    float*  hstart      = (float*)(ws + 174063616);

    convert_kernel<<<16384, 256, 0, stream>>>(x,  xb,  (M_ * D_) / 4);
    convert_kernel<<<1024,  256, 0, stream>>>(Wz, wzb, (H_ * D_) / 4);
    convert_kernel<<<1024,  256, 0, stream>>>(Wh, whb, (H_ * D_) / 4);

    dual_gemm_kernel<<<4096, 256, 0, stream>>>(xb, wzb, whb, bz, bh, av);

    scan_pass1<<<1024, 256, 0, stream>>>(av, chunkAV);
    scan_pass2<<<16,   256, 0, stream>>>(chunkAV, h0, hstart);
    scan_pass3<<<1024, 256, 0, stream>>>(av, hstart, out);
}

// Round 2
// 310.384 us; speedup vs baseline: 1.1945x; 1.1945x over previous
//
#include <hip/hip_runtime.h>
#include <hip/hip_bf16.h>

// Problem constants (from setup_inputs): B=4, T=4096, D=1024, H=1024
#define B_ 4
#define T_ 4096
#define D_ 1024
#define H_ 1024
#define M_ (B_ * T_)   // 16384

typedef __attribute__((ext_vector_type(8))) short short8;   // 8 bf16 = 4 VGPRs (MFMA A/B frag)
typedef __attribute__((ext_vector_type(4))) float f32x4;    // MFMA C/D frag

// ---------------- fp32 -> bf16 (RNE) ----------------
__device__ __forceinline__ unsigned short f2bf(float f) {
    unsigned int u = __float_as_uint(f);
    u += 0x7fffu + ((u >> 16) & 1u);
    return (unsigned short)(u >> 16);
}

// One kernel converts x, Wz, Wh (ranges concatenated).
// x: 4194304 float4 groups, Wz: 262144, Wh: 262144  -> 4718592 total -> 18432 blocks.
__global__ __launch_bounds__(256) void convert_all(
    const float* __restrict__ x, const float* __restrict__ wz, const float* __restrict__ wh,
    unsigned short* __restrict__ xb, unsigned short* __restrict__ wzb, unsigned short* __restrict__ whb)
{
    int i = blockIdx.x * 256 + threadIdx.x;
    const float* s; unsigned short* d; int off;
    if (i < 4194304)      { s = x;  d = xb;  off = i; }
    else if (i < 4456448) { s = wz; d = wzb; off = i - 4194304; }
    else                  { s = wh; d = whb; off = i - 4456448; }
    float4 f = ((const float4*)s)[off];
    ushort4 u;
    u.x = f2bf(f.x); u.y = f2bf(f.y); u.z = f2bf(f.z); u.w = f2bf(f.w);
    ((ushort4*)d)[off] = u;
}

// async global->LDS, 16B per lane; LDS dest = wave-uniform base + lane*16
__device__ __forceinline__ void async16(const void* g, void* l) {
    __builtin_amdgcn_global_load_lds(
        (__attribute__((address_space(1))) void*)g,
        (__attribute__((address_space(3))) void*)l,
        16, 0, 0);
}

// ---------------- fused dual GEMM + epilogue + chunk-summary ----------------
// Block tile 128(M) x 64(N); 4 waves; wave w: m-half = w>>1 (64 rows), n-half = w&1 (32 cols).
// MFMA 16x16x32 bf16; K-step 32.
// LDS fragment-order: subtile = 16 rows x 32 k; lane L holds row (L&15), k-elems (L>>4)*8..+7,
// stored linearly at L*16B -> global_load_lds lane fetches its own fragment; ds_read_b128 linear.
// Epilogue: a = sigmoid(-k), v = sigmoid(k)*g(hb) -> av[m][n] (float2), plus per-chunk affine
// composition (A,V) over the wave's 64 rows (= one full chunk) -> chunkAV (pass1 eliminated).
__global__ __launch_bounds__(256) void dual_gemm_kernel(
    const unsigned short* __restrict__ xb,   // [M][D] bf16
    const unsigned short* __restrict__ wzb,  // [H][D] bf16
    const unsigned short* __restrict__ whb,  // [H][D] bf16
    const float* __restrict__ bz,
    const float* __restrict__ bh,
    float* __restrict__ av,                  // [M][H][2] fp32
    float2* __restrict__ chunkAV)            // [64][B][H]
{
    __shared__ short8 ldsA[8 * 64];          // 8 KB
    __shared__ short8 ldsBz[4 * 64];         // 4 KB
    __shared__ short8 ldsBh[4 * 64];         // 4 KB

    const int tid   = threadIdx.x;
    const int lane  = tid & 63;
    const int w     = tid >> 6;
    const int whalf = w >> 1;
    const int nhalf = w & 1;
    const int mb    = blockIdx.x >> 4;       // 0..127
    const int nb    = blockIdx.x & 15;       // 0..15
    const int r16   = lane & 15;
    const int q     = lane >> 4;

    // staging sources: wave w stages A subtiles {2w, 2w+1}, Bz subtile w, Bh subtile w.
    const unsigned short* gA0 = xb  + (size_t)(mb * 128 + (2 * w) * 16 + r16) * D_ + q * 8;
    const unsigned short* gA1 = gA0 + 16 * D_;
    const unsigned short* gBz = wzb + (size_t)(nb * 64 + w * 16 + r16) * D_ + q * 8;
    const unsigned short* gBh = whb + (size_t)(nb * 64 + w * 16 + r16) * D_ + q * 8;
    short8* lA0 = &ldsA[(2 * w) * 64];       // wave-uniform LDS bases
    short8* lA1 = &ldsA[(2 * w + 1) * 64];
    short8* lBz = &ldsBz[w * 64];
    short8* lBh = &ldsBh[w * 64];

    f32x4 accz[4][2] = {};
    f32x4 acch[4][2] = {};

    for (int kk = 0; kk < D_; kk += 32) {
        __syncthreads();                     // prior iter's ds_reads complete
        async16(gA0 + kk, lA0);
        async16(gA1 + kk, lA1);
        async16(gBz + kk, lBz);
        async16(gBh + kk, lBh);
        __syncthreads();                     // vmcnt(0) drain -> staged data visible

        short8 fa[4], fz[2], fh[2];
#pragma unroll
        for (int gm = 0; gm < 4; ++gm) fa[gm] = ldsA[(whalf * 4 + gm) * 64 + lane];
#pragma unroll
        for (int gn = 0; gn < 2; ++gn) {
            fz[gn] = ldsBz[(nhalf * 2 + gn) * 64 + lane];
            fh[gn] = ldsBh[(nhalf * 2 + gn) * 64 + lane];
        }
#pragma unroll
        for (int gm = 0; gm < 4; ++gm)
#pragma unroll
            for (int gn = 0; gn < 2; ++gn) {
                accz[gm][gn] = __builtin_amdgcn_mfma_f32_16x16x32_bf16(fa[gm], fz[gn], accz[gm][gn], 0, 0, 0);
                acch[gm][gn] = __builtin_amdgcn_mfma_f32_16x16x32_bf16(fa[gm], fh[gn], acch[gm][gn], 0, 0, 0);
            }
    }

    // Epilogue. C/D layout: col = lane&15, row = q*4 + rr  [verified m89/m91]
    const int cglob = mb * 2 + whalf;        // global 64-row chunk id, 0..255
    const int cc = cglob & 63;
    const int bb = cglob >> 6;
#pragma unroll
    for (int gn = 0; gn < 2; ++gn) {
        const int ncol = nb * 64 + nhalf * 32 + gn * 16 + r16;
        const float bzv = bz[ncol];
        const float bhv = bh[ncol];
        float CA = 1.0f, CV = 0.0f;          // chunk composite (applied-first .. last)
#pragma unroll
        for (int gm = 0; gm < 4; ++gm) {
            float LA = 1.0f, LV = 0.0f;      // this lane's 4-row segment
#pragma unroll
            for (int rr = 0; rr < 4; ++rr) {
                float kv = accz[gm][gn][rr] + bzv;
                float hv = acch[gm][gn][rr] + bhv;
                float tk = __expf(-fabsf(kv));
                float ik = 1.0f / (1.0f + tk);
                float sig = (kv >= 0.0f) ? ik : tk * ik;       // sigmoid(k)
                float ac  = (kv >= 0.0f) ? tk * ik : ik;       // sigmoid(-k)
                float th = __expf(-fabsf(hv));
                float ih = 1.0f / (1.0f + th);
                float gh = (hv >= 0.0f) ? (hv + 0.5f) : th * ih; // g(hb)
                float vv = sig * gh;
                const size_t m = (size_t)mb * 128 + whalf * 64 + gm * 16 + q * 4 + rr;
                *(float2*)(av + ((size_t)m * H_ + ncol) * 2) = make_float2(ac, vv);
                LV = ac * LV + vv;           // compose f_t after accumulated (ascending t)
                LA = ac * LA;
            }
            // order-preserving combine across q (segments ordered by q; lower index first)
#pragma unroll
            for (int mask = 16; mask <= 32; mask <<= 1) {
                float PA = __shfl_xor(LA, mask);
                float PV = __shfl_xor(LV, mask);
                if (lane & mask) { LV = LA * PV + LV; LA = LA * PA; }   // mine is later
                else             { LV = PA * LV + PV; LA = PA * LA; }   // partner later
            }
            CV = LA * CV + LV;               // group composite after chunk-so-far
            CA = LA * CA;
        }
        if (q == 0)
            chunkAV[cc * 4096 + bb * 1024 + ncol] = make_float2(CA, CV);
    }
}

// ---------------- scan pass2: sequential over 64 chunk summaries per channel ----------------
__global__ __launch_bounds__(256) void scan_pass2(const float2* __restrict__ chunkAV,
                                                  const float* __restrict__ h0,
                                                  float* __restrict__ hstart) {
    int chan = blockIdx.x * blockDim.x + threadIdx.x;   // 4096 threads
    int n = chan & (H_ - 1);
    int b = chan >> 10;
    float x = h0[b * H_ + n];
    float h;
    if (x >= 0.0f) { h = x + 0.5f; }
    else { float t = __expf(x); h = t / (1.0f + t); }   // g(h0)
#pragma unroll 8
    for (int c = 0; c < 64; ++c) {
        hstart[c * 4096 + chan] = h;
        float2 s = chunkAV[c * 4096 + chan];
        h = s.x * h + s.y;
    }
}

// ---------------- scan pass3: replay each chunk from entry state ----------------
__global__ __launch_bounds__(256) void scan_pass3(const float* __restrict__ av,
                                                  const float* __restrict__ hstart,
                                                  float* __restrict__ out) {
    int g = blockIdx.x * blockDim.x + threadIdx.x;
    int n = g & (H_ - 1);
    int rest = g >> 10;
    int c = rest & 63;
    int b = rest >> 6;
    float h = hstart[c * 4096 + b * 1024 + n];
    const float2* base = (const float2*)av + ((size_t)(b * T_ + c * 64)) * H_ + n;
    float* obase = out + ((size_t)(b * T_ + c * 64)) * H_ + n;
#pragma unroll 8
    for (int t = 0; t < 64; ++t) {
        float2 p = base[(size_t)t * H_];
        h = p.x * h + p.y;
        obase[(size_t)t * H_] = h;
    }
}

// ---------------- launch ----------------
extern "C" void kernel_launch(void* const* d_in, const int* in_sizes, int n_in,
                              void* d_out, int out_size, void* d_ws, size_t ws_size,
                              hipStream_t stream) {
    const float* x  = (const float*)d_in[0];   // [B,T,D]
    const float* h0 = (const float*)d_in[1];   // [B,H]
    const float* Wz = (const float*)d_in[2];   // [H,D]
    const float* bz = (const float*)d_in[3];   // [H]
    const float* Wh = (const float*)d_in[4];   // [H,D]
    const float* bh = (const float*)d_in[5];   // [H]
    float* out = (float*)d_out;

    // workspace layout (bytes):
    //   xb  bf16 [M][D]            @ 0          33,554,432
    //   wzb bf16 [H][D]            @ 33554432    2,097,152
    //   whb bf16 [H][D]            @ 35651584    2,097,152
    //   av  fp32 [M][H][2]         @ 37748736  134,217,728
    //   chunkAV float2 [64][B][H]  @ 171966464   2,097,152
    //   hstart fp32 [64][B*H]      @ 174063616   1,048,576
    char* ws = (char*)d_ws;
    unsigned short* xb  = (unsigned short*)(ws);
    unsigned short* wzb = (unsigned short*)(ws + 33554432);
    unsigned short* whb = (unsigned short*)(ws + 35651584);
    float*  av          = (float*)(ws + 37748736);
    float2* chunkAV     = (float2*)(ws + 171966464);
    float*  hstart      = (float*)(ws + 174063616);

    convert_all<<<18432, 256, 0, stream>>>(x, Wz, Wh, xb, wzb, whb);

    dual_gemm_kernel<<<2048, 256, 0, stream>>>(xb, wzb, whb, bz, bh, av, chunkAV);

    scan_pass2<<<16,   256, 0, stream>>>(chunkAV, h0, hstart);
    scan_pass3<<<1024, 256, 0, stream>>>(av, hstart, out);
}

// Round 3
// 295.888 us; speedup vs baseline: 1.2530x; 1.0490x over previous
//
#include <hip/hip_runtime.h>
#include <hip/hip_bf16.h>
#include <hip/hip_fp16.h>

// Problem constants (from setup_inputs): B=4, T=4096, D=1024, H=1024
#define B_ 4
#define T_ 4096
#define D_ 1024
#define H_ 1024
#define M_ (B_ * T_)   // 16384

typedef __attribute__((ext_vector_type(8))) short short8;   // 8 bf16 = 4 VGPRs (MFMA A/B frag)
typedef __attribute__((ext_vector_type(4))) float f32x4;    // MFMA C/D frag

// ---------------- fp32 -> bf16 (RNE) ----------------
__device__ __forceinline__ unsigned short f2bf(float f) {
    unsigned int u = __float_as_uint(f);
    u += 0x7fffu + ((u >> 16) & 1u);
    return (unsigned short)(u >> 16);
}

// One kernel converts x, Wz, Wh (ranges concatenated).
__global__ __launch_bounds__(256) void convert_all(
    const float* __restrict__ x, const float* __restrict__ wz, const float* __restrict__ wh,
    unsigned short* __restrict__ xb, unsigned short* __restrict__ wzb, unsigned short* __restrict__ whb)
{
    int i = blockIdx.x * 256 + threadIdx.x;
    const float* s; unsigned short* d; int off;
    if (i < 4194304)      { s = x;  d = xb;  off = i; }
    else if (i < 4456448) { s = wz; d = wzb; off = i - 4194304; }
    else                  { s = wh; d = whb; off = i - 4456448; }
    float4 f = ((const float4*)s)[off];
    ushort4 u;
    u.x = f2bf(f.x); u.y = f2bf(f.y); u.z = f2bf(f.z); u.w = f2bf(f.w);
    ((ushort4*)d)[off] = u;
}

// async global->LDS, 16B per lane; LDS dest = wave-uniform base + lane*16
__device__ __forceinline__ void async16(const void* g, void* l) {
    __builtin_amdgcn_global_load_lds(
        (__attribute__((address_space(1))) void*)g,
        (__attribute__((address_space(3))) void*)l,
        16, 0, 0);
}

// ---------------- fused dual GEMM + epilogue + chunk-summary ----------------
// Block tile 128(M) x 64(N), BK=64 (16 K-iters, 32 MFMA/wave/iter, 2 barriers/iter).
// 4 waves; wave w: whalf = w>>1 (64 rows), nhalf = w&1 (32 cols).
// LDS fragment-order subtiles (16 rows x 32 k): lane L holds row (L&15), k (L>>4)*8..+7,
// linear at L*16B -> async16 stages each lane's own fragment; ds_read_b128 conflict-benign.
// Epilogue: a = sigmoid(-k), v = sigmoid(k)*g(hb) -> av16[m][n] = half2(a,v), plus per-64-chunk
// affine composition -> chunkAV (fp32).
__global__ __launch_bounds__(256) void dual_gemm_kernel(
    const unsigned short* __restrict__ xb,   // [M][D] bf16
    const unsigned short* __restrict__ wzb,  // [H][D] bf16
    const unsigned short* __restrict__ whb,  // [H][D] bf16
    const float* __restrict__ bz,
    const float* __restrict__ bh,
    __half2* __restrict__ av16,              // [M][H] half2(a,v)
    float2* __restrict__ chunkAV)            // [64][B][H]
{
    __shared__ short8 ldsA[16 * 64];         // 16 KB: (rg 0..7, kh 0..1)
    __shared__ short8 ldsBz[8 * 64];         // 8 KB:  (rg 0..3, kh 0..1)
    __shared__ short8 ldsBh[8 * 64];         // 8 KB

    const int tid   = threadIdx.x;
    const int lane  = tid & 63;
    const int w     = tid >> 6;
    const int whalf = w >> 1;
    const int nhalf = w & 1;
    const int nb    = blockIdx.x >> 7;       // 0..15  (nb-major: consecutive blocks share B)
    const int mb    = blockIdx.x & 127;      // 0..127
    const int r16   = lane & 15;
    const int q     = lane >> 4;

    // staging: wave w stages A-blocks 4w..4w+3 (j -> rg=j>>1, kh=j&1), Bz/Bh blocks 2w,2w+1.
    const unsigned short* gA[4];
    short8* lA[4];
#pragma unroll
    for (int i = 0; i < 4; ++i) {
        const int j  = 4 * w + i;
        const int rg = j >> 1, kh = j & 1;
        gA[i] = xb + (size_t)(mb * 128 + rg * 16 + r16) * D_ + kh * 32 + q * 8;
        lA[i] = &ldsA[j * 64];
    }
    const unsigned short* gBz[2]; const unsigned short* gBh[2];
    short8 *lBz[2], *lBh[2];
#pragma unroll
    for (int i = 0; i < 2; ++i) {
        const int j  = 2 * w + i;
        const int rg = j >> 1, kh = j & 1;
        gBz[i] = wzb + (size_t)(nb * 64 + rg * 16 + r16) * D_ + kh * 32 + q * 8;
        gBh[i] = whb + (size_t)(nb * 64 + rg * 16 + r16) * D_ + kh * 32 + q * 8;
        lBz[i] = &ldsBz[j * 64];
        lBh[i] = &ldsBh[j * 64];
    }

    f32x4 accz[4][2] = {};
    f32x4 acch[4][2] = {};

    for (int kk = 0; kk < D_; kk += 64) {
        __syncthreads();                     // prior iter's ds_reads complete (WAR)
#pragma unroll
        for (int i = 0; i < 4; ++i) async16(gA[i] + kk, lA[i]);
#pragma unroll
        for (int i = 0; i < 2; ++i) { async16(gBz[i] + kk, lBz[i]); async16(gBh[i] + kk, lBh[i]); }
        __syncthreads();                     // staged data visible

#pragma unroll
        for (int kh = 0; kh < 2; ++kh) {     // only one k-half of frags live at a time
            short8 fa[4], fz[2], fh[2];
#pragma unroll
            for (int gm = 0; gm < 4; ++gm)
                fa[gm] = ldsA[((whalf * 4 + gm) * 2 + kh) * 64 + lane];
#pragma unroll
            for (int gn = 0; gn < 2; ++gn) {
                fz[gn] = ldsBz[((nhalf * 2 + gn) * 2 + kh) * 64 + lane];
                fh[gn] = ldsBh[((nhalf * 2 + gn) * 2 + kh) * 64 + lane];
            }
#pragma unroll
            for (int gm = 0; gm < 4; ++gm)
#pragma unroll
                for (int gn = 0; gn < 2; ++gn) {
                    accz[gm][gn] = __builtin_amdgcn_mfma_f32_16x16x32_bf16(fa[gm], fz[gn], accz[gm][gn], 0, 0, 0);
                    acch[gm][gn] = __builtin_amdgcn_mfma_f32_16x16x32_bf16(fa[gm], fh[gn], acch[gm][gn], 0, 0, 0);
                }
        }
    }

    // Epilogue. C/D layout: col = lane&15, row = q*4 + rr  [verified m89/m91]
    const int cglob = mb * 2 + whalf;        // global 64-row chunk id, 0..255
    const int cc = cglob & 63;
    const int bb = cglob >> 6;
#pragma unroll
    for (int gn = 0; gn < 2; ++gn) {
        const int ncol = nb * 64 + nhalf * 32 + gn * 16 + r16;
        const float bzv = bz[ncol];
        const float bhv = bh[ncol];
        float CA = 1.0f, CV = 0.0f;          // chunk composite
#pragma unroll
        for (int gm = 0; gm < 4; ++gm) {
            float LA = 1.0f, LV = 0.0f;      // this lane's 4-row segment
#pragma unroll
            for (int rr = 0; rr < 4; ++rr) {
                float kv = accz[gm][gn][rr] + bzv;
                float hv = acch[gm][gn][rr] + bhv;
                float tk = __expf(-fabsf(kv));
                float ik = 1.0f / (1.0f + tk);
                float sig = (kv >= 0.0f) ? ik : tk * ik;         // sigmoid(k)
                float ac  = (kv >= 0.0f) ? tk * ik : ik;         // sigmoid(-k)
                float th = __expf(-fabsf(hv));
                float ih = 1.0f / (1.0f + th);
                float gh = (hv >= 0.0f) ? (hv + 0.5f) : th * ih; // g(hb)
                float vv = sig * gh;
                const size_t m = (size_t)mb * 128 + whalf * 64 + gm * 16 + q * 4 + rr;
                av16[(size_t)m * H_ + ncol] = __floats2half2_rn(ac, vv);
                LV = ac * LV + vv;           // ascending t composition
                LA = ac * LA;
            }
            // order-preserving combine across q (lower lane index = earlier segment)
#pragma unroll
            for (int mask = 16; mask <= 32; mask <<= 1) {
                float PA = __shfl_xor(LA, mask);
                float PV = __shfl_xor(LV, mask);
                if (lane & mask) { LV = LA * PV + LV; LA = LA * PA; }
                else             { LV = PA * LV + PV; LA = PA * LA; }
            }
            CV = LA * CV + LV;
            CA = LA * CA;
        }
        if (q == 0)
            chunkAV[cc * 4096 + bb * 1024 + ncol] = make_float2(CA, CV);
    }
}

// ---------------- scan pass2: sequential over 64 chunk summaries per channel ----------------
__global__ __launch_bounds__(256) void scan_pass2(const float2* __restrict__ chunkAV,
                                                  const float* __restrict__ h0,
                                                  float* __restrict__ hstart) {
    int chan = blockIdx.x * blockDim.x + threadIdx.x;   // 4096 threads
    int n = chan & (H_ - 1);
    int b = chan >> 10;
    float x = h0[b * H_ + n];
    float h;
    if (x >= 0.0f) { h = x + 0.5f; }
    else { float t = __expf(x); h = t / (1.0f + t); }   // g(h0)
#pragma unroll 8
    for (int c = 0; c < 64; ++c) {
        hstart[c * 4096 + chan] = h;
        float2 s = chunkAV[c * 4096 + chan];
        h = s.x * h + s.y;
    }
}

// ---------------- scan pass3: replay each chunk from entry state ----------------
__global__ __launch_bounds__(256) void scan_pass3(const __half2* __restrict__ av16,
                                                  const float* __restrict__ hstart,
                                                  float* __restrict__ out) {
    int g = blockIdx.x * blockDim.x + threadIdx.x;
    int n = g & (H_ - 1);
    int rest = g >> 10;
    int c = rest & 63;
    int b = rest >> 6;
    float h = hstart[c * 4096 + b * 1024 + n];
    const __half2* base = av16 + ((size_t)(b * T_ + c * 64)) * H_ + n;
    float* obase = out + ((size_t)(b * T_ + c * 64)) * H_ + n;
#pragma unroll 8
    for (int t = 0; t < 64; ++t) {
        float2 p = __half22float2(base[(size_t)t * H_]);
        h = p.x * h + p.y;
        obase[(size_t)t * H_] = h;
    }
}

// ---------------- launch ----------------
extern "C" void kernel_launch(void* const* d_in, const int* in_sizes, int n_in,
                              void* d_out, int out_size, void* d_ws, size_t ws_size,
                              hipStream_t stream) {
    const float* x  = (const float*)d_in[0];   // [B,T,D]
    const float* h0 = (const float*)d_in[1];   // [B,H]
    const float* Wz = (const float*)d_in[2];   // [H,D]
    const float* bz = (const float*)d_in[3];   // [H]
    const float* Wh = (const float*)d_in[4];   // [H,D]
    const float* bh = (const float*)d_in[5];   // [H]
    float* out = (float*)d_out;

    // workspace layout (bytes):
    //   xb  bf16 [M][D]            @ 0            33,554,432
    //   wzb bf16 [H][D]            @ 33554432      2,097,152
    //   whb bf16 [H][D]            @ 35651584      2,097,152
    //   av16 half2 [M][H]          @ 37748736     67,108,864
    //   chunkAV float2 [64][B][H]  @ 104857600     2,097,152
    //   hstart fp32 [64][B*H]      @ 106954752     1,048,576
    char* ws = (char*)d_ws;
    unsigned short* xb  = (unsigned short*)(ws);
    unsigned short* wzb = (unsigned short*)(ws + 33554432);
    unsigned short* whb = (unsigned short*)(ws + 35651584);
    __half2* av16       = (__half2*)(ws + 37748736);
    float2* chunkAV     = (float2*)(ws + 104857600);
    float*  hstart      = (float*)(ws + 106954752);

    convert_all<<<18432, 256, 0, stream>>>(x, Wz, Wh, xb, wzb, whb);

    dual_gemm_kernel<<<2048, 256, 0, stream>>>(xb, wzb, whb, bz, bh, av16, chunkAV);

    scan_pass2<<<16,   256, 0, stream>>>(chunkAV, h0, hstart);
    scan_pass3<<<1024, 256, 0, stream>>>(av16, hstart, out);
}